// Round 5
// baseline (577.532 us; speedup 1.0000x reference)
//
#include <hip/hip_runtime.h>
#include <hip/hip_bf16.h>

#define N_NODES 40000
#define N_EDGES 640000
#define FDIM 128
#define N_GRAPHS 64
#define NEG_SLOPE 0.01f

// ---------------- helpers ----------------
__device__ __forceinline__ float leaky(float v) {
    return v > 0.0f ? v : NEG_SLOPE * v;
}
__device__ __forceinline__ void fma4(float4& d, float a, const float4& b) {
    d.x += a * b.x; d.y += a * b.y; d.z += a * b.z; d.w += a * b.w;
}
__device__ __forceinline__ int clamp_idx(int v) {
    return min(max(v, 0), N_NODES - 1);
}

// ---------------- CSR build ----------------
// NOTE: integer inputs are delivered as int32 by the harness (NOT int64).
// Indices defensively clamped: no-op for valid data, prevents core-dump
// (and preserves diagnosability) if the dtype contract ever differs.
__global__ void k_count(const int* __restrict__ ei, const float* __restrict__ ew,
                        float* __restrict__ deg, int* __restrict__ cnt) {
    int e = blockIdx.x * blockDim.x + threadIdx.x;
    if (e >= N_EDGES) return;
    int c = clamp_idx(ei[N_EDGES + e]);
    atomicAdd(&cnt[c], 1);
    atomicAdd(&deg[c], ew[e]);
}

__global__ void k_dinv(const float* __restrict__ deg, float* __restrict__ dinv) {
    int i = blockIdx.x * blockDim.x + threadIdx.x;
    if (i >= N_NODES) return;
    dinv[i] = rsqrtf(deg[i] + 1.0f);   // +1 self-loop weight; deg+1 >= 1 > 0 always
}

// block sums of cnt over chunks of 1024
__global__ void k_scan1(const int* __restrict__ cnt, int* __restrict__ bsums) {
    __shared__ int sdata[256];
    int tid = threadIdx.x;
    int base = blockIdx.x * 1024 + tid * 4;
    int s = 0;
    #pragma unroll
    for (int j = 0; j < 4; ++j)
        if (base + j < N_NODES) s += cnt[base + j];
    sdata[tid] = s;
    __syncthreads();
    for (int off = 128; off > 0; off >>= 1) {
        if (tid < off) sdata[tid] += sdata[tid + off];
        __syncthreads();
    }
    if (tid == 0) bsums[blockIdx.x] = sdata[0];
}

// exclusive scan of 40 block sums (single thread; tiny)
__global__ void k_scan2(int* __restrict__ bsums, int* __restrict__ colptr) {
    if (threadIdx.x == 0 && blockIdx.x == 0) {
        int running = 0;
        for (int b = 0; b < 40; ++b) {
            int t = bsums[b];
            bsums[b] = running;
            running += t;
        }
        colptr[N_NODES] = running;   // == N_EDGES
    }
}

__global__ void k_scan3(const int* __restrict__ cnt, const int* __restrict__ bsums,
                        int* __restrict__ colptr, int* __restrict__ fillpos) {
    __shared__ int sdata[256];
    int tid = threadIdx.x;
    int base = blockIdx.x * 1024 + tid * 4;
    int v[4];
    int tsum = 0;
    #pragma unroll
    for (int j = 0; j < 4; ++j) {
        v[j] = (base + j < N_NODES) ? cnt[base + j] : 0;
        tsum += v[j];
    }
    sdata[tid] = tsum;
    __syncthreads();
    // Hillis-Steele inclusive scan over 256
    for (int off = 1; off < 256; off <<= 1) {
        int t = (tid >= off) ? sdata[tid - off] : 0;
        __syncthreads();
        sdata[tid] += t;
        __syncthreads();
    }
    int run = sdata[tid] - tsum + bsums[blockIdx.x];
    #pragma unroll
    for (int j = 0; j < 4; ++j) {
        if (base + j < N_NODES) {
            colptr[base + j] = run;
            fillpos[base + j] = run;
            run += v[j];
        }
    }
}

// packed edge record: .x = row index (int bits), .y = coef
__global__ void k_fill(const int* __restrict__ ei, const float* __restrict__ ew,
                       const float* __restrict__ dinv, int* __restrict__ fillpos,
                       float2* __restrict__ epack) {
    int e = blockIdx.x * blockDim.x + threadIdx.x;
    if (e >= N_EDGES) return;
    int r = clamp_idx(ei[e]);
    int c = clamp_idx(ei[N_EDGES + e]);
    int pos = atomicAdd(&fillpos[c], 1);
    float2 p;
    p.x = __int_as_float(r);
    p.y = dinv[r] * ew[e] * dinv[c];
    epack[pos] = p;
}

// ---------------- GEMM: C[n,128] = act(A[n,128]) @ W[128,128] ----------------
// 128x128 block tile, K chunked by 64, XOR-swizzled LDS granules.
// Lane tx owns output cols [tx*4, tx*4+3] (accL) and [64+tx*4, 64+tx*4+3] (accR):
// Ws read indices tx^c and 16+(tx^c) hit 8 distinct bank groups -> 2-way (free).
__global__ __launch_bounds__(256) void k_gemm(const float* __restrict__ A,
                                              const float* __restrict__ W,
                                              float* __restrict__ C, int n, int act) {
    __shared__ float4 As[128 * 16];  // [m][k4] chunk of 64 k, swizzled
    __shared__ float4 Ws[64 * 32];   // [k][n4] chunk of 64 k, swizzled
    const int tid = threadIdx.x;
    const int bm = blockIdx.x * 128;
    const int tx = tid & 15, ty = tid >> 4;

    float4 accL[8], accR[8];
    #pragma unroll
    for (int i = 0; i < 8; ++i) {
        accL[i] = make_float4(0.f, 0.f, 0.f, 0.f);
        accR[i] = make_float4(0.f, 0.f, 0.f, 0.f);
    }

    for (int kt = 0; kt < 2; ++kt) {
        __syncthreads();
        // stage A chunk (apply activation on load)
        for (int i = tid; i < 2048; i += 256) {
            int m = i >> 4, k4 = i & 15;
            int row = bm + m;
            float4 v = make_float4(0.f, 0.f, 0.f, 0.f);
            if (row < n) v = *reinterpret_cast<const float4*>(A + (size_t)row * 128 + kt * 64 + k4 * 4);
            if (act) { v.x = leaky(v.x); v.y = leaky(v.y); v.z = leaky(v.z); v.w = leaky(v.w); }
            As[m * 16 + (k4 ^ ((m >> 3) & 7))] = v;
        }
        // stage W chunk
        for (int i = tid; i < 2048; i += 256) {
            int k = i >> 5, n4 = i & 31;
            float4 v = *reinterpret_cast<const float4*>(W + (size_t)(kt * 64 + k) * 128 + n4 * 4);
            Ws[k * 32 + (n4 ^ (k & 7))] = v;
        }
        __syncthreads();

        #pragma unroll
        for (int kk = 0; kk < 16; ++kk) {
            float a_s[8][4];
            #pragma unroll
            for (int i = 0; i < 8; ++i) {
                float4 v = As[(ty * 8 + i) * 16 + (kk ^ (ty & 7))];
                a_s[i][0] = v.x; a_s[i][1] = v.y; a_s[i][2] = v.z; a_s[i][3] = v.w;
            }
            float4 wl[4], wr[4];
            #pragma unroll
            for (int kj = 0; kj < 4; ++kj) {
                int k = kk * 4 + kj;
                int c = k & 7;
                int fl = tx ^ c;            // cols tx*4..+3
                wl[kj] = Ws[k * 32 + fl];
                wr[kj] = Ws[k * 32 + 16 + fl];  // cols 64+tx*4..+3 ((tx+16)^c == 16|(tx^c))
            }
            #pragma unroll
            for (int kj = 0; kj < 4; ++kj) {
                #pragma unroll
                for (int i = 0; i < 8; ++i) {
                    float av = a_s[i][kj];
                    fma4(accL[i], av, wl[kj]);
                    fma4(accR[i], av, wr[kj]);
                }
            }
        }
    }

    #pragma unroll
    for (int i = 0; i < 8; ++i) {
        int row = bm + ty * 8 + i;
        if (row < n) {
            *reinterpret_cast<float4*>(C + (size_t)row * 128 + tx * 4)      = accL[i];
            *reinterpret_cast<float4*>(C + (size_t)row * 128 + 64 + tx * 4) = accR[i];
        }
    }
}

// ---------------- aggregate: out[i] = b + dinv[i]^2*h[i] + sum_e coef*h[row] ----------------
// one wave per node; lane holds float2 of the 128-wide feature row
__global__ void k_aggregate(const float* __restrict__ h, const int* __restrict__ colptr,
                            const float2* __restrict__ epack,
                            const float* __restrict__ dinv, const float* __restrict__ bias,
                            float* __restrict__ out) {
    int wave = (blockIdx.x * blockDim.x + threadIdx.x) >> 6;
    int lane = threadIdx.x & 63;
    if (wave >= N_NODES) return;
    int i = wave;
    int s = colptr[i], e = colptr[i + 1];
    float di = dinv[i];
    float selfc = di * di;
    float2 hv = reinterpret_cast<const float2*>(h + (size_t)i * 128)[lane];
    float2 bb = reinterpret_cast<const float2*>(bias)[lane];
    float accx = bb.x + selfc * hv.x;
    float accy = bb.y + selfc * hv.y;
    // unroll x2: two independent gather chains in flight
    int j = s;
    for (; j + 1 < e; j += 2) {
        float2 p0 = epack[j];
        float2 p1 = epack[j + 1];
        int r0 = __float_as_int(p0.x);
        int r1 = __float_as_int(p1.x);
        float2 v0 = reinterpret_cast<const float2*>(h + (size_t)r0 * 128)[lane];
        float2 v1 = reinterpret_cast<const float2*>(h + (size_t)r1 * 128)[lane];
        accx += p0.y * v0.x;
        accy += p0.y * v0.y;
        accx += p1.y * v1.x;
        accy += p1.y * v1.y;
    }
    if (j < e) {
        float2 p0 = epack[j];
        int r0 = __float_as_int(p0.x);
        float2 v0 = reinterpret_cast<const float2*>(h + (size_t)r0 * 128)[lane];
        accx += p0.y * v0.x;
        accy += p0.y * v0.y;
    }
    float2 acc; acc.x = accx; acc.y = accy;
    reinterpret_cast<float2*>(out + (size_t)i * 128)[lane] = acc;
}

// ---------------- mean pool over sorted batch ----------------
__device__ __forceinline__ int lbound(const int* b, int n, int v) {
    int lo = 0, hi = n;
    while (lo < hi) {
        int mid = (lo + hi) >> 1;
        if (b[mid] < v) lo = mid + 1; else hi = mid;
    }
    return lo;
}

__global__ void k_pool(const float* __restrict__ h, const int* __restrict__ batch,
                       float* __restrict__ g) {
    __shared__ int bnd[2];
    __shared__ float part[256];
    int tid = threadIdx.x;
    int graph = blockIdx.x;
    if (tid == 0) {
        bnd[0] = lbound(batch, N_NODES, graph);
        bnd[1] = lbound(batch, N_NODES, graph + 1);
    }
    __syncthreads();
    int lo = bnd[0], hi = bnd[1];
    int f = tid & 127, half = tid >> 7;
    float s = 0.0f;
    for (int i = lo + half; i < hi; i += 2) s += h[(size_t)i * 128 + f];
    part[tid] = s;
    __syncthreads();
    if (half == 0) {
        float tot = part[f] + part[128 + f];
        float c = (float)(hi - lo);
        g[graph * 128 + f] = tot / fmaxf(c, 1.0f);
    }
}

// ---------------- MLP head: 128 -> 64 -> 32 -> 2 ----------------
__global__ void k_mlp(const float* __restrict__ g,
                      const float* __restrict__ fw1, const float* __restrict__ fb1,
                      const float* __restrict__ fw2, const float* __restrict__ fb2,
                      const float* __restrict__ fw3, const float* __restrict__ fb3,
                      float* __restrict__ out) {
    __shared__ float gs[128], h1[64], h2[32];
    int graph = blockIdx.x;
    int tid = threadIdx.x;  // 64 threads
    gs[tid] = g[graph * 128 + tid];
    gs[tid + 64] = g[graph * 128 + 64 + tid];
    __syncthreads();
    float acc = fb1[tid];
    #pragma unroll 4
    for (int k = 0; k < 128; ++k) acc += gs[k] * fw1[k * 64 + tid];
    h1[tid] = leaky(acc);
    __syncthreads();
    if (tid < 32) {
        float a2 = fb2[tid];
        #pragma unroll 4
        for (int k = 0; k < 64; ++k) a2 += h1[k] * fw2[k * 32 + tid];
        h2[tid] = leaky(a2);
    }
    __syncthreads();
    if (tid < 2) {
        float a3 = fb3[tid];
        #pragma unroll
        for (int k = 0; k < 32; ++k) a3 += h2[k] * fw3[k * 2 + tid];
        out[graph * 2 + tid] = a3;
    }
}

// ---------------- launch ----------------
extern "C" void kernel_launch(void* const* d_in, const int* in_sizes, int n_in,
                              void* d_out, int out_size, void* d_ws, size_t ws_size,
                              hipStream_t stream) {
    const float* x   = (const float*)d_in[0];
    const int*   ei  = (const int*)d_in[1];    // int32 per harness contract
    const float* ew  = (const float*)d_in[2];
    const int*   bt  = (const int*)d_in[3];    // int32 per harness contract
    const float* W0 = (const float*)d_in[4];
    const float* b0 = (const float*)d_in[5];
    const float* W1 = (const float*)d_in[6];
    const float* b1 = (const float*)d_in[7];
    const float* W2 = (const float*)d_in[8];
    const float* b2 = (const float*)d_in[9];
    const float* fw1 = (const float*)d_in[10];
    const float* fb1 = (const float*)d_in[11];
    const float* fw2 = (const float*)d_in[12];
    const float* fb2 = (const float*)d_in[13];
    const float* fw3 = (const float*)d_in[14];
    const float* fb3 = (const float*)d_in[15];
    float* out = (float*)d_out;

    // workspace carve (512-B aligned)
    char* w = (char*)d_ws;
    size_t off = 0;
    auto carve = [&](size_t bytes) -> void* {
        void* p = w + off;
        off += (bytes + 511) & ~(size_t)511;
        return p;
    };
    float*  deg     = (float*)carve((size_t)N_NODES * 4);
    float*  dinv    = (float*)carve((size_t)N_NODES * 4);
    int*    cnt     = (int*)carve((size_t)N_NODES * 4);
    int*    colptr  = (int*)carve((size_t)(N_NODES + 1) * 4);
    int*    fillpos = (int*)carve((size_t)N_NODES * 4);
    int*    bsums   = (int*)carve(64 * 4);
    float2* epack   = (float2*)carve((size_t)N_EDGES * 8);
    float*  hA      = (float*)carve((size_t)N_NODES * FDIM * 4);
    float*  hB      = (float*)carve((size_t)N_NODES * FDIM * 4);
    float*  gpool   = (float*)carve((size_t)N_GRAPHS * FDIM * 4);
    (void)ws_size; (void)n_in; (void)in_sizes; (void)out_size;

    // ---- CSR build (once; shared by all 3 convs) ----
    hipMemsetAsync(deg, 0, (size_t)N_NODES * 4, stream);
    hipMemsetAsync(cnt, 0, (size_t)N_NODES * 4, stream);
    k_count<<<(N_EDGES + 255) / 256, 256, 0, stream>>>(ei, ew, deg, cnt);
    k_dinv<<<(N_NODES + 255) / 256, 256, 0, stream>>>(deg, dinv);
    k_scan1<<<40, 256, 0, stream>>>(cnt, bsums);
    k_scan2<<<1, 64, 0, stream>>>(bsums, colptr);
    k_scan3<<<40, 256, 0, stream>>>(cnt, bsums, colptr, fillpos);
    k_fill<<<(N_EDGES + 255) / 256, 256, 0, stream>>>(ei, ew, dinv, fillpos, epack);

    const int gemm_blocks = (N_NODES + 127) / 128;       // 313
    const int agg_blocks  = (N_NODES * 64 + 255) / 256;  // one wave per node

    // conv1
    k_gemm<<<gemm_blocks, 256, 0, stream>>>(x, W0, hA, N_NODES, 0);
    k_aggregate<<<agg_blocks, 256, 0, stream>>>(hA, colptr, epack, dinv, b0, hB);
    // conv2 (leaky fused into GEMM input)
    k_gemm<<<gemm_blocks, 256, 0, stream>>>(hB, W1, hA, N_NODES, 1);
    k_aggregate<<<agg_blocks, 256, 0, stream>>>(hA, colptr, epack, dinv, b1, hB);
    // conv3
    k_gemm<<<gemm_blocks, 256, 0, stream>>>(hB, W2, hA, N_NODES, 1);
    k_aggregate<<<agg_blocks, 256, 0, stream>>>(hA, colptr, epack, dinv, b2, hB);

    // pool + MLP
    k_pool<<<N_GRAPHS, 256, 0, stream>>>(hB, bt, gpool);
    k_mlp<<<N_GRAPHS, 64, 0, stream>>>(gpool, fw1, fb1, fw2, fb2, fw3, fb3, out);
}

// Round 9
// 509.872 us; speedup vs baseline: 1.1327x; 1.1327x over previous
//
#include <hip/hip_runtime.h>
#include <hip/hip_bf16.h>

#define N_NODES 40000
#define N_EDGES 640000
#define FDIM 128
#define N_GRAPHS 64
#define NEG_SLOPE 0.01f

// ---------------- helpers ----------------
__device__ __forceinline__ float leaky(float v) {
    return v > 0.0f ? v : NEG_SLOPE * v;
}
__device__ __forceinline__ void fma4(float4& d, float a, const float4& b) {
    d.x += a * b.x; d.y += a * b.y; d.z += a * b.z; d.w += a * b.w;
}
__device__ __forceinline__ int clamp_idx(int v) {
    return min(max(v, 0), N_NODES - 1);
}

// ---------------- CSR build ----------------
// NOTE: integer inputs are delivered as int32 by the harness (NOT int64).
__global__ void k_count(const int* __restrict__ ei, const float* __restrict__ ew,
                        float* __restrict__ deg, int* __restrict__ cnt) {
    int e = blockIdx.x * blockDim.x + threadIdx.x;
    if (e >= N_EDGES) return;
    int c = clamp_idx(ei[N_EDGES + e]);
    atomicAdd(&cnt[c], 1);
    atomicAdd(&deg[c], ew[e]);
}

__global__ void k_dinv(const float* __restrict__ deg, float* __restrict__ dinv) {
    int i = blockIdx.x * blockDim.x + threadIdx.x;
    if (i >= N_NODES) return;
    dinv[i] = rsqrtf(deg[i] + 1.0f);   // +1 self-loop weight; deg+1 >= 1 > 0 always
}

// block sums of cnt over chunks of 1024
__global__ void k_scan1(const int* __restrict__ cnt, int* __restrict__ bsums) {
    __shared__ int sdata[256];
    int tid = threadIdx.x;
    int base = blockIdx.x * 1024 + tid * 4;
    int s = 0;
    #pragma unroll
    for (int j = 0; j < 4; ++j)
        if (base + j < N_NODES) s += cnt[base + j];
    sdata[tid] = s;
    __syncthreads();
    for (int off = 128; off > 0; off >>= 1) {
        if (tid < off) sdata[tid] += sdata[tid + off];
        __syncthreads();
    }
    if (tid == 0) bsums[blockIdx.x] = sdata[0];
}

// exclusive scan of 40 block sums (single thread; tiny)
__global__ void k_scan2(int* __restrict__ bsums, int* __restrict__ colptr) {
    if (threadIdx.x == 0 && blockIdx.x == 0) {
        int running = 0;
        for (int b = 0; b < 40; ++b) {
            int t = bsums[b];
            bsums[b] = running;
            running += t;
        }
        colptr[N_NODES] = running;   // == N_EDGES
    }
}

__global__ void k_scan3(const int* __restrict__ cnt, const int* __restrict__ bsums,
                        int* __restrict__ colptr, int* __restrict__ fillpos) {
    __shared__ int sdata[256];
    int tid = threadIdx.x;
    int base = blockIdx.x * 1024 + tid * 4;
    int v[4];
    int tsum = 0;
    #pragma unroll
    for (int j = 0; j < 4; ++j) {
        v[j] = (base + j < N_NODES) ? cnt[base + j] : 0;
        tsum += v[j];
    }
    sdata[tid] = tsum;
    __syncthreads();
    // Hillis-Steele inclusive scan over 256
    for (int off = 1; off < 256; off <<= 1) {
        int t = (tid >= off) ? sdata[tid - off] : 0;
        __syncthreads();
        sdata[tid] += t;
        __syncthreads();
    }
    int run = sdata[tid] - tsum + bsums[blockIdx.x];
    #pragma unroll
    for (int j = 0; j < 4; ++j) {
        if (base + j < N_NODES) {
            colptr[base + j] = run;
            fillpos[base + j] = run;
            run += v[j];
        }
    }
}

// packed edge record: .x = row index (int bits), .y = coef
__global__ void k_fill(const int* __restrict__ ei, const float* __restrict__ ew,
                       const float* __restrict__ dinv, int* __restrict__ fillpos,
                       float2* __restrict__ epack) {
    int e = blockIdx.x * blockDim.x + threadIdx.x;
    if (e >= N_EDGES) return;
    int r = clamp_idx(ei[e]);
    int c = clamp_idx(ei[N_EDGES + e]);
    int pos = atomicAdd(&fillpos[c], 1);
    float2 p;
    p.x = __int_as_float(r);
    p.y = dinv[r] * ew[e] * dinv[c];
    epack[pos] = p;
}

// ---------------- GEMM: C[n,128] = act(A[n,128]) @ W[128,128] ----------------
__global__ __launch_bounds__(256) void k_gemm(const float* __restrict__ A,
                                              const float* __restrict__ W,
                                              float* __restrict__ C, int n, int act) {
    __shared__ float4 As[128 * 16];  // [m][k4] chunk of 64 k, swizzled
    __shared__ float4 Ws[64 * 32];   // [k][n4] chunk of 64 k, swizzled
    const int tid = threadIdx.x;
    const int bm = blockIdx.x * 128;
    const int tx = tid & 15, ty = tid >> 4;

    float4 accL[8], accR[8];
    #pragma unroll
    for (int i = 0; i < 8; ++i) {
        accL[i] = make_float4(0.f, 0.f, 0.f, 0.f);
        accR[i] = make_float4(0.f, 0.f, 0.f, 0.f);
    }

    for (int kt = 0; kt < 2; ++kt) {
        __syncthreads();
        // stage A chunk (apply activation on load)
        for (int i = tid; i < 2048; i += 256) {
            int m = i >> 4, k4 = i & 15;
            int row = bm + m;
            float4 v = make_float4(0.f, 0.f, 0.f, 0.f);
            if (row < n) v = *reinterpret_cast<const float4*>(A + (size_t)row * 128 + kt * 64 + k4 * 4);
            if (act) { v.x = leaky(v.x); v.y = leaky(v.y); v.z = leaky(v.z); v.w = leaky(v.w); }
            As[m * 16 + (k4 ^ ((m >> 3) & 7))] = v;
        }
        // stage W chunk
        for (int i = tid; i < 2048; i += 256) {
            int k = i >> 5, n4 = i & 31;
            float4 v = *reinterpret_cast<const float4*>(W + (size_t)(kt * 64 + k) * 128 + n4 * 4);
            Ws[k * 32 + (n4 ^ (k & 7))] = v;
        }
        __syncthreads();

        #pragma unroll
        for (int kk = 0; kk < 16; ++kk) {
            float a_s[8][4];
            #pragma unroll
            for (int i = 0; i < 8; ++i) {
                float4 v = As[(ty * 8 + i) * 16 + (kk ^ (ty & 7))];
                a_s[i][0] = v.x; a_s[i][1] = v.y; a_s[i][2] = v.z; a_s[i][3] = v.w;
            }
            float4 wl[4], wr[4];
            #pragma unroll
            for (int kj = 0; kj < 4; ++kj) {
                int k = kk * 4 + kj;
                int c = k & 7;
                int fl = tx ^ c;            // cols tx*4..+3
                wl[kj] = Ws[k * 32 + fl];
                wr[kj] = Ws[k * 32 + 16 + fl];  // cols 64+tx*4..+3
            }
            #pragma unroll
            for (int kj = 0; kj < 4; ++kj) {
                #pragma unroll
                for (int i = 0; i < 8; ++i) {
                    float av = a_s[i][kj];
                    fma4(accL[i], av, wl[kj]);
                    fma4(accR[i], av, wr[kj]);
                }
            }
        }
    }

    #pragma unroll
    for (int i = 0; i < 8; ++i) {
        int row = bm + ty * 8 + i;
        if (row < n) {
            *reinterpret_cast<float4*>(C + (size_t)row * 128 + tx * 4)      = accL[i];
            *reinterpret_cast<float4*>(C + (size_t)row * 128 + 64 + tx * 4) = accR[i];
        }
    }
}

// ---------------- aggregate: out[i] = b + dinv[i]^2*h[i] + sum_e coef*h[row] ----------------
// one 32-lane HALF-WAVE per node; lane holds float4 (16B) of the 512B feature row.
// 2 nodes per wave -> ~40% fewer issued loads/loop-ops chip-wide vs 64-lane/node.
// Edge accumulation order per output element unchanged (numerics identical).
__global__ void k_aggregate(const float* __restrict__ h, const int* __restrict__ colptr,
                            const float2* __restrict__ epack,
                            const float* __restrict__ dinv, const float* __restrict__ bias,
                            float* __restrict__ out) {
    int node = (blockIdx.x * blockDim.x + threadIdx.x) >> 5;
    int lane = threadIdx.x & 31;
    if (node >= N_NODES) return;
    int s = colptr[node], e = colptr[node + 1];
    float di = dinv[node];
    float selfc = di * di;
    float4 hv = reinterpret_cast<const float4*>(h + (size_t)node * 128)[lane];
    float4 bb = reinterpret_cast<const float4*>(bias)[lane];
    float4 acc;
    acc.x = bb.x + selfc * hv.x;
    acc.y = bb.y + selfc * hv.y;
    acc.z = bb.z + selfc * hv.z;
    acc.w = bb.w + selfc * hv.w;
    // unroll x2: two independent gather chains in flight
    int j = s;
    for (; j + 1 < e; j += 2) {
        float2 p0 = epack[j];
        float2 p1 = epack[j + 1];
        int r0 = __float_as_int(p0.x);
        int r1 = __float_as_int(p1.x);
        float4 v0 = reinterpret_cast<const float4*>(h + (size_t)r0 * 128)[lane];
        float4 v1 = reinterpret_cast<const float4*>(h + (size_t)r1 * 128)[lane];
        fma4(acc, p0.y, v0);
        fma4(acc, p1.y, v1);
    }
    if (j < e) {
        float2 p0 = epack[j];
        int r0 = __float_as_int(p0.x);
        float4 v0 = reinterpret_cast<const float4*>(h + (size_t)r0 * 128)[lane];
        fma4(acc, p0.y, v0);
    }
    reinterpret_cast<float4*>(out + (size_t)node * 128)[lane] = acc;
}

// ---------------- mean pool, stage 1: segmented partial sums ----------------
// 313 blocks x 256 threads; block owns 128 nodes; thread owns column f over
// rows base+half, base+half+2, ... Run-accumulates while batch[i] constant
// (batch sorted -> wave-uniform branch), one atomicAdd per run.
__global__ void k_pool1(const float* __restrict__ h, const int* __restrict__ batch,
                        float* __restrict__ gsum) {
    int base = blockIdx.x * 128;
    int tid = threadIdx.x;
    int f = tid & 127, half = tid >> 7;
    int end = min(base + 128, N_NODES);
    float acc = 0.0f;
    int cur = -1;
    for (int i = base + half; i < end; i += 2) {
        int g = batch[i];
        if (g != cur) {
            if (cur >= 0) atomicAdd(&gsum[cur * 128 + f], acc);
            acc = 0.0f;
            cur = g;
        }
        acc += h[(size_t)i * 128 + f];
    }
    if (cur >= 0) atomicAdd(&gsum[cur * 128 + f], acc);
}

// ---------------- MLP head: mean-divide + 128 -> 64 -> 32 -> 2 ----------------
__device__ __forceinline__ int lbound(const int* b, int n, int v) {
    int lo = 0, hi = n;
    while (lo < hi) {
        int mid = (lo + hi) >> 1;
        if (b[mid] < v) lo = mid + 1; else hi = mid;
    }
    return lo;
}

__global__ void k_mlp(const float* __restrict__ gsum, const int* __restrict__ batch,
                      const float* __restrict__ fw1, const float* __restrict__ fb1,
                      const float* __restrict__ fw2, const float* __restrict__ fb2,
                      const float* __restrict__ fw3, const float* __restrict__ fb3,
                      float* __restrict__ out) {
    __shared__ float gs[128], h1[64], h2[32];
    __shared__ float rcnt;
    int graph = blockIdx.x;
    int tid = threadIdx.x;  // 64 threads
    if (tid == 0) {
        int lo = lbound(batch, N_NODES, graph);
        int hi = lbound(batch, N_NODES, graph + 1);
        rcnt = 1.0f / fmaxf((float)(hi - lo), 1.0f);
    }
    __syncthreads();
    float rc = rcnt;
    gs[tid]      = gsum[graph * 128 + tid] * rc;
    gs[tid + 64] = gsum[graph * 128 + 64 + tid] * rc;
    __syncthreads();
    float acc = fb1[tid];
    #pragma unroll 4
    for (int k = 0; k < 128; ++k) acc += gs[k] * fw1[k * 64 + tid];
    h1[tid] = leaky(acc);
    __syncthreads();
    if (tid < 32) {
        float a2 = fb2[tid];
        #pragma unroll 4
        for (int k = 0; k < 64; ++k) a2 += h1[k] * fw2[k * 32 + tid];
        h2[tid] = leaky(a2);
    }
    __syncthreads();
    if (tid < 2) {
        float a3 = fb3[tid];
        #pragma unroll
        for (int k = 0; k < 32; ++k) a3 += h2[k] * fw3[k * 2 + tid];
        out[graph * 2 + tid] = a3;
    }
}

// ---------------- launch ----------------
extern "C" void kernel_launch(void* const* d_in, const int* in_sizes, int n_in,
                              void* d_out, int out_size, void* d_ws, size_t ws_size,
                              hipStream_t stream) {
    const float* x   = (const float*)d_in[0];
    const int*   ei  = (const int*)d_in[1];    // int32 per harness contract
    const float* ew  = (const float*)d_in[2];
    const int*   bt  = (const int*)d_in[3];    // int32 per harness contract
    const float* W0 = (const float*)d_in[4];
    const float* b0 = (const float*)d_in[5];
    const float* W1 = (const float*)d_in[6];
    const float* b1 = (const float*)d_in[7];
    const float* W2 = (const float*)d_in[8];
    const float* b2 = (const float*)d_in[9];
    const float* fw1 = (const float*)d_in[10];
    const float* fb1 = (const float*)d_in[11];
    const float* fw2 = (const float*)d_in[12];
    const float* fb2 = (const float*)d_in[13];
    const float* fw3 = (const float*)d_in[14];
    const float* fb3 = (const float*)d_in[15];
    float* out = (float*)d_out;

    // workspace carve (512-B aligned)
    char* w = (char*)d_ws;
    size_t off = 0;
    auto carve = [&](size_t bytes) -> void* {
        void* p = w + off;
        off += (bytes + 511) & ~(size_t)511;
        return p;
    };
    float*  deg     = (float*)carve((size_t)N_NODES * 4);
    float*  dinv    = (float*)carve((size_t)N_NODES * 4);
    int*    cnt     = (int*)carve((size_t)N_NODES * 4);
    int*    colptr  = (int*)carve((size_t)(N_NODES + 1) * 4);
    int*    fillpos = (int*)carve((size_t)N_NODES * 4);
    int*    bsums   = (int*)carve(64 * 4);
    float2* epack   = (float2*)carve((size_t)N_EDGES * 8);
    float*  hA      = (float*)carve((size_t)N_NODES * FDIM * 4);
    float*  hB      = (float*)carve((size_t)N_NODES * FDIM * 4);
    float*  gsum    = (float*)carve((size_t)N_GRAPHS * FDIM * 4);
    (void)ws_size; (void)n_in; (void)in_sizes; (void)out_size;

    // ---- CSR build (once; shared by all 3 convs) ----
    hipMemsetAsync(deg, 0, (size_t)N_NODES * 4, stream);
    hipMemsetAsync(cnt, 0, (size_t)N_NODES * 4, stream);
    hipMemsetAsync(gsum, 0, (size_t)N_GRAPHS * FDIM * 4, stream);
    k_count<<<(N_EDGES + 255) / 256, 256, 0, stream>>>(ei, ew, deg, cnt);
    k_dinv<<<(N_NODES + 255) / 256, 256, 0, stream>>>(deg, dinv);
    k_scan1<<<40, 256, 0, stream>>>(cnt, bsums);
    k_scan2<<<1, 64, 0, stream>>>(bsums, colptr);
    k_scan3<<<40, 256, 0, stream>>>(cnt, bsums, colptr, fillpos);
    k_fill<<<(N_EDGES + 255) / 256, 256, 0, stream>>>(ei, ew, dinv, fillpos, epack);

    const int gemm_blocks = (N_NODES + 127) / 128;       // 313
    const int agg_blocks  = (N_NODES * 32 + 255) / 256;  // one 32-lane half-wave per node

    // conv1
    k_gemm<<<gemm_blocks, 256, 0, stream>>>(x, W0, hA, N_NODES, 0);
    k_aggregate<<<agg_blocks, 256, 0, stream>>>(hA, colptr, epack, dinv, b0, hB);
    // conv2 (leaky fused into GEMM input)
    k_gemm<<<gemm_blocks, 256, 0, stream>>>(hB, W1, hA, N_NODES, 1);
    k_aggregate<<<agg_blocks, 256, 0, stream>>>(hA, colptr, epack, dinv, b1, hB);
    // conv3
    k_gemm<<<gemm_blocks, 256, 0, stream>>>(hB, W2, hA, N_NODES, 1);
    k_aggregate<<<agg_blocks, 256, 0, stream>>>(hA, colptr, epack, dinv, b2, hB);

    // pool (parallel partial sums) + MLP (mean-divide fused)
    k_pool1<<<(N_NODES + 127) / 128, 256, 0, stream>>>(hB, bt, gsum);
    k_mlp<<<N_GRAPHS, 64, 0, stream>>>(gsum, bt, fw1, fb1, fw2, fb2, fw3, fb3, out);
}

// Round 10
// 490.679 us; speedup vs baseline: 1.1770x; 1.0391x over previous
//
#include <hip/hip_runtime.h>
#include <hip/hip_bf16.h>

#define N_NODES 40000
#define N_EDGES 640000
#define FDIM 128
#define N_GRAPHS 64
#define NEG_SLOPE 0.01f
#define DEG_SCALE 16777216.0f   // 2^24 fixed-point for packed degree
#define DEG_MASK  ((1ULL << 40) - 1)

// ---------------- helpers ----------------
__device__ __forceinline__ float leaky(float v) {
    return v > 0.0f ? v : NEG_SLOPE * v;
}
__device__ __forceinline__ void fma4(float4& d, float a, const float4& b) {
    d.x += a * b.x; d.y += a * b.y; d.z += a * b.z; d.w += a * b.w;
}
__device__ __forceinline__ int clamp_idx(int v) {
    return min(max(v, 0), N_NODES - 1);
}

// ---------------- CSR build ----------------
// NOTE: integer inputs are delivered as int32 by the harness (NOT int64).
// Single packed u64 atomic per edge: cnt in bits [40,64), deg (2^-24 fixed
// point) in bits [0,40). Max deg sum ~64*2^24 << 2^40 -> no overflow.
__global__ void k_count(const int* __restrict__ ei, const float* __restrict__ ew,
                        unsigned long long* __restrict__ pack) {
    int e = blockIdx.x * blockDim.x + threadIdx.x;
    if (e >= N_EDGES) return;
    int c = clamp_idx(ei[N_EDGES + e]);
    unsigned long long fp = (unsigned long long)__float2uint_rn(ew[e] * DEG_SCALE);
    atomicAdd(&pack[c], (1ULL << 40) | fp);
}

// decode pack -> dinv (float) and cnt (int) for the scan
__global__ void k_dinv(const unsigned long long* __restrict__ pack,
                       float* __restrict__ dinv, int* __restrict__ cnt) {
    int i = blockIdx.x * blockDim.x + threadIdx.x;
    if (i >= N_NODES) return;
    unsigned long long p = pack[i];
    float deg = (float)(p & DEG_MASK) * (1.0f / DEG_SCALE);
    dinv[i] = rsqrtf(deg + 1.0f);   // +1 self-loop weight
    cnt[i] = (int)(p >> 40);
}

// block sums of cnt over chunks of 1024
__global__ void k_scan1(const int* __restrict__ cnt, int* __restrict__ bsums) {
    __shared__ int sdata[256];
    int tid = threadIdx.x;
    int base = blockIdx.x * 1024 + tid * 4;
    int s = 0;
    #pragma unroll
    for (int j = 0; j < 4; ++j)
        if (base + j < N_NODES) s += cnt[base + j];
    sdata[tid] = s;
    __syncthreads();
    for (int off = 128; off > 0; off >>= 1) {
        if (tid < off) sdata[tid] += sdata[tid + off];
        __syncthreads();
    }
    if (tid == 0) bsums[blockIdx.x] = sdata[0];
}

// exclusive scan of 40 block sums (single thread; tiny)
__global__ void k_scan2(int* __restrict__ bsums, int* __restrict__ colptr) {
    if (threadIdx.x == 0 && blockIdx.x == 0) {
        int running = 0;
        for (int b = 0; b < 40; ++b) {
            int t = bsums[b];
            bsums[b] = running;
            running += t;
        }
        colptr[N_NODES] = running;   // == N_EDGES
    }
}

__global__ void k_scan3(const int* __restrict__ cnt, const int* __restrict__ bsums,
                        int* __restrict__ colptr, int* __restrict__ fillpos) {
    __shared__ int sdata[256];
    int tid = threadIdx.x;
    int base = blockIdx.x * 1024 + tid * 4;
    int v[4];
    int tsum = 0;
    #pragma unroll
    for (int j = 0; j < 4; ++j) {
        v[j] = (base + j < N_NODES) ? cnt[base + j] : 0;
        tsum += v[j];
    }
    sdata[tid] = tsum;
    __syncthreads();
    // Hillis-Steele inclusive scan over 256
    for (int off = 1; off < 256; off <<= 1) {
        int t = (tid >= off) ? sdata[tid - off] : 0;
        __syncthreads();
        sdata[tid] += t;
        __syncthreads();
    }
    int run = sdata[tid] - tsum + bsums[blockIdx.x];
    #pragma unroll
    for (int j = 0; j < 4; ++j) {
        if (base + j < N_NODES) {
            colptr[base + j] = run;
            fillpos[base + j] = run;
            run += v[j];
        }
    }
}

// packed edge record: .x = row index (int bits), .y = dinv[row]*w  (dinv[col]
// factored out of the per-edge coef; applied once per node in k_aggregate)
__global__ void k_fill(const int* __restrict__ ei, const float* __restrict__ ew,
                       const float* __restrict__ dinv, int* __restrict__ fillpos,
                       float2* __restrict__ epack) {
    int e = blockIdx.x * blockDim.x + threadIdx.x;
    if (e >= N_EDGES) return;
    int r = clamp_idx(ei[e]);
    int c = clamp_idx(ei[N_EDGES + e]);
    int pos = atomicAdd(&fillpos[c], 1);
    float2 p;
    p.x = __int_as_float(r);
    p.y = dinv[r] * ew[e];
    epack[pos] = p;
}

// ---------------- GEMM: C[n,128] = act(A[n,128]) @ W[128,128] ----------------
__global__ __launch_bounds__(256) void k_gemm(const float* __restrict__ A,
                                              const float* __restrict__ W,
                                              float* __restrict__ C, int n, int act) {
    __shared__ float4 As[128 * 16];  // [m][k4] chunk of 64 k, swizzled
    __shared__ float4 Ws[64 * 32];   // [k][n4] chunk of 64 k, swizzled
    const int tid = threadIdx.x;
    const int bm = blockIdx.x * 128;
    const int tx = tid & 15, ty = tid >> 4;

    float4 accL[8], accR[8];
    #pragma unroll
    for (int i = 0; i < 8; ++i) {
        accL[i] = make_float4(0.f, 0.f, 0.f, 0.f);
        accR[i] = make_float4(0.f, 0.f, 0.f, 0.f);
    }

    for (int kt = 0; kt < 2; ++kt) {
        __syncthreads();
        // stage A chunk (apply activation on load)
        for (int i = tid; i < 2048; i += 256) {
            int m = i >> 4, k4 = i & 15;
            int row = bm + m;
            float4 v = make_float4(0.f, 0.f, 0.f, 0.f);
            if (row < n) v = *reinterpret_cast<const float4*>(A + (size_t)row * 128 + kt * 64 + k4 * 4);
            if (act) { v.x = leaky(v.x); v.y = leaky(v.y); v.z = leaky(v.z); v.w = leaky(v.w); }
            As[m * 16 + (k4 ^ ((m >> 3) & 7))] = v;
        }
        // stage W chunk
        for (int i = tid; i < 2048; i += 256) {
            int k = i >> 5, n4 = i & 31;
            float4 v = *reinterpret_cast<const float4*>(W + (size_t)(kt * 64 + k) * 128 + n4 * 4);
            Ws[k * 32 + (n4 ^ (k & 7))] = v;
        }
        __syncthreads();

        #pragma unroll
        for (int kk = 0; kk < 16; ++kk) {
            float a_s[8][4];
            #pragma unroll
            for (int i = 0; i < 8; ++i) {
                float4 v = As[(ty * 8 + i) * 16 + (kk ^ (ty & 7))];
                a_s[i][0] = v.x; a_s[i][1] = v.y; a_s[i][2] = v.z; a_s[i][3] = v.w;
            }
            float4 wl[4], wr[4];
            #pragma unroll
            for (int kj = 0; kj < 4; ++kj) {
                int k = kk * 4 + kj;
                int c = k & 7;
                int fl = tx ^ c;            // cols tx*4..+3
                wl[kj] = Ws[k * 32 + fl];
                wr[kj] = Ws[k * 32 + 16 + fl];  // cols 64+tx*4..+3
            }
            #pragma unroll
            for (int kj = 0; kj < 4; ++kj) {
                #pragma unroll
                for (int i = 0; i < 8; ++i) {
                    float av = a_s[i][kj];
                    fma4(accL[i], av, wl[kj]);
                    fma4(accR[i], av, wr[kj]);
                }
            }
        }
    }

    #pragma unroll
    for (int i = 0; i < 8; ++i) {
        int row = bm + ty * 8 + i;
        if (row < n) {
            *reinterpret_cast<float4*>(C + (size_t)row * 128 + tx * 4)      = accL[i];
            *reinterpret_cast<float4*>(C + (size_t)row * 128 + 64 + tx * 4) = accR[i];
        }
    }
}

// ---------------- aggregate ----------------
// out[i] = b + dinv[i]^2*h[i] + dinv[i] * sum_e (dinv[r]*w)*h[r]
// one 32-lane half-wave per node; lane holds float4 (16B) of the 512B row.
__global__ void k_aggregate(const float* __restrict__ h, const int* __restrict__ colptr,
                            const float2* __restrict__ epack,
                            const float* __restrict__ dinv, const float* __restrict__ bias,
                            float* __restrict__ out) {
    int node = (blockIdx.x * blockDim.x + threadIdx.x) >> 5;
    int lane = threadIdx.x & 31;
    if (node >= N_NODES) return;
    int s = colptr[node], e = colptr[node + 1];
    float di = dinv[node];
    float selfc = di * di;
    float4 hv = reinterpret_cast<const float4*>(h + (size_t)node * 128)[lane];
    float4 bb = reinterpret_cast<const float4*>(bias)[lane];
    float4 acc = make_float4(0.f, 0.f, 0.f, 0.f);   // edge sum (dinv[i] applied at end)
    // unroll x2: two independent gather chains in flight
    int j = s;
    for (; j + 1 < e; j += 2) {
        float2 p0 = epack[j];
        float2 p1 = epack[j + 1];
        int r0 = __float_as_int(p0.x);
        int r1 = __float_as_int(p1.x);
        float4 v0 = reinterpret_cast<const float4*>(h + (size_t)r0 * 128)[lane];
        float4 v1 = reinterpret_cast<const float4*>(h + (size_t)r1 * 128)[lane];
        fma4(acc, p0.y, v0);
        fma4(acc, p1.y, v1);
    }
    if (j < e) {
        float2 p0 = epack[j];
        int r0 = __float_as_int(p0.x);
        float4 v0 = reinterpret_cast<const float4*>(h + (size_t)r0 * 128)[lane];
        fma4(acc, p0.y, v0);
    }
    float4 o;
    o.x = bb.x + selfc * hv.x + di * acc.x;
    o.y = bb.y + selfc * hv.y + di * acc.y;
    o.z = bb.z + selfc * hv.z + di * acc.z;
    o.w = bb.w + selfc * hv.w + di * acc.w;
    reinterpret_cast<float4*>(out + (size_t)node * 128)[lane] = o;
}

// ---------------- mean pool, stage 1: segmented partial sums ----------------
__global__ void k_pool1(const float* __restrict__ h, const int* __restrict__ batch,
                        float* __restrict__ gsum) {
    int base = blockIdx.x * 128;
    int tid = threadIdx.x;
    int f = tid & 127, half = tid >> 7;
    int end = min(base + 128, N_NODES);
    float acc = 0.0f;
    int cur = -1;
    for (int i = base + half; i < end; i += 2) {
        int g = batch[i];
        if (g != cur) {
            if (cur >= 0) atomicAdd(&gsum[cur * 128 + f], acc);
            acc = 0.0f;
            cur = g;
        }
        acc += h[(size_t)i * 128 + f];
    }
    if (cur >= 0) atomicAdd(&gsum[cur * 128 + f], acc);
}

// ---------------- MLP head: mean-divide + 128 -> 64 -> 32 -> 2 ----------------
__device__ __forceinline__ int lbound(const int* b, int n, int v) {
    int lo = 0, hi = n;
    while (lo < hi) {
        int mid = (lo + hi) >> 1;
        if (b[mid] < v) lo = mid + 1; else hi = mid;
    }
    return lo;
}

__global__ void k_mlp(const float* __restrict__ gsum, const int* __restrict__ batch,
                      const float* __restrict__ fw1, const float* __restrict__ fb1,
                      const float* __restrict__ fw2, const float* __restrict__ fb2,
                      const float* __restrict__ fw3, const float* __restrict__ fb3,
                      float* __restrict__ out) {
    __shared__ float gs[128], h1[64], h2[32];
    __shared__ float rcnt;
    int graph = blockIdx.x;
    int tid = threadIdx.x;  // 64 threads
    if (tid == 0) {
        int lo = lbound(batch, N_NODES, graph);
        int hi = lbound(batch, N_NODES, graph + 1);
        rcnt = 1.0f / fmaxf((float)(hi - lo), 1.0f);
    }
    __syncthreads();
    float rc = rcnt;
    gs[tid]      = gsum[graph * 128 + tid] * rc;
    gs[tid + 64] = gsum[graph * 128 + 64 + tid] * rc;
    __syncthreads();
    float acc = fb1[tid];
    #pragma unroll 4
    for (int k = 0; k < 128; ++k) acc += gs[k] * fw1[k * 64 + tid];
    h1[tid] = leaky(acc);
    __syncthreads();
    if (tid < 32) {
        float a2 = fb2[tid];
        #pragma unroll 4
        for (int k = 0; k < 64; ++k) a2 += h1[k] * fw2[k * 32 + tid];
        h2[tid] = leaky(a2);
    }
    __syncthreads();
    if (tid < 2) {
        float a3 = fb3[tid];
        #pragma unroll
        for (int k = 0; k < 32; ++k) a3 += h2[k] * fw3[k * 2 + tid];
        out[graph * 2 + tid] = a3;
    }
}

// ---------------- launch ----------------
extern "C" void kernel_launch(void* const* d_in, const int* in_sizes, int n_in,
                              void* d_out, int out_size, void* d_ws, size_t ws_size,
                              hipStream_t stream) {
    const float* x   = (const float*)d_in[0];
    const int*   ei  = (const int*)d_in[1];    // int32 per harness contract
    const float* ew  = (const float*)d_in[2];
    const int*   bt  = (const int*)d_in[3];    // int32 per harness contract
    const float* W0 = (const float*)d_in[4];
    const float* b0 = (const float*)d_in[5];
    const float* W1 = (const float*)d_in[6];
    const float* b1 = (const float*)d_in[7];
    const float* W2 = (const float*)d_in[8];
    const float* b2 = (const float*)d_in[9];
    const float* fw1 = (const float*)d_in[10];
    const float* fb1 = (const float*)d_in[11];
    const float* fw2 = (const float*)d_in[12];
    const float* fb2 = (const float*)d_in[13];
    const float* fw3 = (const float*)d_in[14];
    const float* fb3 = (const float*)d_in[15];
    float* out = (float*)d_out;

    // workspace carve (512-B aligned)
    char* w = (char*)d_ws;
    size_t off = 0;
    auto carve = [&](size_t bytes) -> void* {
        void* p = w + off;
        off += (bytes + 511) & ~(size_t)511;
        return p;
    };
    unsigned long long* pack = (unsigned long long*)carve((size_t)N_NODES * 8);
    float*  dinv    = (float*)carve((size_t)N_NODES * 4);
    int*    cnt     = (int*)carve((size_t)N_NODES * 4);
    int*    colptr  = (int*)carve((size_t)(N_NODES + 1) * 4);
    int*    fillpos = (int*)carve((size_t)N_NODES * 4);
    int*    bsums   = (int*)carve(64 * 4);
    float2* epack   = (float2*)carve((size_t)N_EDGES * 8);
    float*  hA      = (float*)carve((size_t)N_NODES * FDIM * 4);
    float*  hB      = (float*)carve((size_t)N_NODES * FDIM * 4);
    float*  gsum    = (float*)carve((size_t)N_GRAPHS * FDIM * 4);
    (void)ws_size; (void)n_in; (void)in_sizes; (void)out_size;

    // ---- CSR build (once; shared by all 3 convs) ----
    hipMemsetAsync(pack, 0, (size_t)N_NODES * 8, stream);
    hipMemsetAsync(gsum, 0, (size_t)N_GRAPHS * FDIM * 4, stream);
    k_count<<<(N_EDGES + 255) / 256, 256, 0, stream>>>(ei, ew, pack);
    k_dinv<<<(N_NODES + 255) / 256, 256, 0, stream>>>(pack, dinv, cnt);
    k_scan1<<<40, 256, 0, stream>>>(cnt, bsums);
    k_scan2<<<1, 64, 0, stream>>>(bsums, colptr);
    k_scan3<<<40, 256, 0, stream>>>(cnt, bsums, colptr, fillpos);
    k_fill<<<(N_EDGES + 255) / 256, 256, 0, stream>>>(ei, ew, dinv, fillpos, epack);

    const int gemm_blocks = (N_NODES + 127) / 128;       // 313
    const int agg_blocks  = (N_NODES * 32 + 255) / 256;  // one 32-lane half-wave per node

    // conv1
    k_gemm<<<gemm_blocks, 256, 0, stream>>>(x, W0, hA, N_NODES, 0);
    k_aggregate<<<agg_blocks, 256, 0, stream>>>(hA, colptr, epack, dinv, b0, hB);
    // conv2 (leaky fused into GEMM input)
    k_gemm<<<gemm_blocks, 256, 0, stream>>>(hB, W1, hA, N_NODES, 1);
    k_aggregate<<<agg_blocks, 256, 0, stream>>>(hA, colptr, epack, dinv, b1, hB);
    // conv3
    k_gemm<<<gemm_blocks, 256, 0, stream>>>(hB, W2, hA, N_NODES, 1);
    k_aggregate<<<agg_blocks, 256, 0, stream>>>(hA, colptr, epack, dinv, b2, hB);

    // pool (parallel partial sums) + MLP (mean-divide fused)
    k_pool1<<<(N_NODES + 127) / 128, 256, 0, stream>>>(hB, bt, gsum);
    k_mlp<<<N_GRAPHS, 64, 0, stream>>>(gsum, bt, fw1, fb1, fw2, fb2, fw3, fb3, out);
}

// Round 14
// 445.639 us; speedup vs baseline: 1.2960x; 1.1011x over previous
//
#include <hip/hip_runtime.h>
#include <hip/hip_bf16.h>

#define N_NODES 40000
#define N_EDGES 640000
#define FDIM 128
#define N_GRAPHS 64
#define NEG_SLOPE 0.01f
#define DEG_SCALE 16777216.0f   // 2^24 fixed-point for packed degree
#define DEG_MASK  ((1ULL << 40) - 1)

// ---------------- helpers ----------------
__device__ __forceinline__ float leaky(float v) {
    return v > 0.0f ? v : NEG_SLOPE * v;
}
__device__ __forceinline__ void fma4(float4& d, float a, const float4& b) {
    d.x += a * b.x; d.y += a * b.y; d.z += a * b.z; d.w += a * b.w;
}
__device__ __forceinline__ int clamp_idx(int v) {
    return min(max(v, 0), N_NODES - 1);
}

// ---------------- CSR build ----------------
// NOTE: integer inputs are delivered as int32 by the harness (NOT int64).
// Single packed u64 atomic per edge: cnt in bits [40,64), deg (2^-24 fixed
// point) in bits [0,40). Max deg sum ~64*2^24 << 2^40 -> no overflow.
__global__ void k_count(const int* __restrict__ ei, const float* __restrict__ ew,
                        unsigned long long* __restrict__ pack) {
    int e = blockIdx.x * blockDim.x + threadIdx.x;
    if (e >= N_EDGES) return;
    int c = clamp_idx(ei[N_EDGES + e]);
    unsigned long long fp = (unsigned long long)__float2uint_rn(ew[e] * DEG_SCALE);
    atomicAdd(&pack[c], (1ULL << 40) | fp);
}

// decode pack -> dinv (float) and cnt (int) for the scan
__global__ void k_dinv(const unsigned long long* __restrict__ pack,
                       float* __restrict__ dinv, int* __restrict__ cnt) {
    int i = blockIdx.x * blockDim.x + threadIdx.x;
    if (i >= N_NODES) return;
    unsigned long long p = pack[i];
    float deg = (float)(p & DEG_MASK) * (1.0f / DEG_SCALE);
    dinv[i] = rsqrtf(deg + 1.0f);   // +1 self-loop weight
    cnt[i] = (int)(p >> 40);
}

// block sums of cnt over chunks of 1024
__global__ void k_scan1(const int* __restrict__ cnt, int* __restrict__ bsums) {
    __shared__ int sdata[256];
    int tid = threadIdx.x;
    int base = blockIdx.x * 1024 + tid * 4;
    int s = 0;
    #pragma unroll
    for (int j = 0; j < 4; ++j)
        if (base + j < N_NODES) s += cnt[base + j];
    sdata[tid] = s;
    __syncthreads();
    for (int off = 128; off > 0; off >>= 1) {
        if (tid < off) sdata[tid] += sdata[tid + off];
        __syncthreads();
    }
    if (tid == 0) bsums[blockIdx.x] = sdata[0];
}

// exclusive scan of 40 block sums (single thread; tiny)
__global__ void k_scan2(int* __restrict__ bsums, int* __restrict__ colptr) {
    if (threadIdx.x == 0 && blockIdx.x == 0) {
        int running = 0;
        for (int b = 0; b < 40; ++b) {
            int t = bsums[b];
            bsums[b] = running;
            running += t;
        }
        colptr[N_NODES] = running;   // == N_EDGES
    }
}

__global__ void k_scan3(const int* __restrict__ cnt, const int* __restrict__ bsums,
                        int* __restrict__ colptr, int* __restrict__ fillpos) {
    __shared__ int sdata[256];
    int tid = threadIdx.x;
    int base = blockIdx.x * 1024 + tid * 4;
    int v[4];
    int tsum = 0;
    #pragma unroll
    for (int j = 0; j < 4; ++j) {
        v[j] = (base + j < N_NODES) ? cnt[base + j] : 0;
        tsum += v[j];
    }
    sdata[tid] = tsum;
    __syncthreads();
    // Hillis-Steele inclusive scan over 256
    for (int off = 1; off < 256; off <<= 1) {
        int t = (tid >= off) ? sdata[tid - off] : 0;
        __syncthreads();
        sdata[tid] += t;
        __syncthreads();
    }
    int run = sdata[tid] - tsum + bsums[blockIdx.x];
    #pragma unroll
    for (int j = 0; j < 4; ++j) {
        if (base + j < N_NODES) {
            colptr[base + j] = run;
            fillpos[base + j] = run;
            run += v[j];
        }
    }
}

// packed edge record: .x = row index (int bits), .y = dinv[row]*w  (dinv[col]
// factored out of the per-edge coef; applied once per node in k_aggregate)
__global__ void k_fill(const int* __restrict__ ei, const float* __restrict__ ew,
                       const float* __restrict__ dinv, int* __restrict__ fillpos,
                       float2* __restrict__ epack) {
    int e = blockIdx.x * blockDim.x + threadIdx.x;
    if (e >= N_EDGES) return;
    int r = clamp_idx(ei[e]);
    int c = clamp_idx(ei[N_EDGES + e]);
    int pos = atomicAdd(&fillpos[c], 1);
    float2 p;
    p.x = __int_as_float(r);
    p.y = dinv[r] * ew[e];
    epack[pos] = p;
}

// ---------------- GEMM: C[n,128] = act(A[n,128]) @ W[128,128] ----------------
// BM=64 tile (was 128): LDS 48 KB -> 3 blocks/CU, grid 625 -> 2-3 blocks
// resident per CU so staging of one block overlaps compute of another.
// ty (16 groups) owns 4 rows; tx (16 lanes) owns cols tx*4..+3 and 64+tx*4..+3.
__global__ __launch_bounds__(256) void k_gemm(const float* __restrict__ A,
                                              const float* __restrict__ W,
                                              float* __restrict__ C, int n, int act) {
    __shared__ float4 As[64 * 16];   // 16 KB: [m][k4] chunk of 64 k, swizzled
    __shared__ float4 Ws[64 * 32];   // 32 KB: [k][n4] chunk of 64 k, swizzled
    const int tid = threadIdx.x;
    const int bm = blockIdx.x * 64;
    const int tx = tid & 15, ty = tid >> 4;

    float4 accL[4], accR[4];
    #pragma unroll
    for (int i = 0; i < 4; ++i) {
        accL[i] = make_float4(0.f, 0.f, 0.f, 0.f);
        accR[i] = make_float4(0.f, 0.f, 0.f, 0.f);
    }

    for (int kt = 0; kt < 2; ++kt) {
        __syncthreads();
        // stage A chunk: 1024 float4s, 4 per thread (activation on load)
        for (int i = tid; i < 1024; i += 256) {
            int m = i >> 4, k4 = i & 15;
            int row = bm + m;
            float4 v = make_float4(0.f, 0.f, 0.f, 0.f);
            if (row < n) v = *reinterpret_cast<const float4*>(A + (size_t)row * 128 + kt * 64 + k4 * 4);
            if (act) { v.x = leaky(v.x); v.y = leaky(v.y); v.z = leaky(v.z); v.w = leaky(v.w); }
            As[m * 16 + (k4 ^ ((m >> 3) & 7))] = v;
        }
        // stage W chunk: 2048 float4s, 8 per thread
        for (int i = tid; i < 2048; i += 256) {
            int k = i >> 5, n4 = i & 31;
            float4 v = *reinterpret_cast<const float4*>(W + (size_t)(kt * 64 + k) * 128 + n4 * 4);
            Ws[k * 32 + (n4 ^ (k & 7))] = v;
        }
        __syncthreads();

        #pragma unroll
        for (int kk = 0; kk < 16; ++kk) {
            float a_s[4][4];
            #pragma unroll
            for (int i = 0; i < 4; ++i) {
                int m = ty * 4 + i;
                float4 v = As[m * 16 + (kk ^ ((m >> 3) & 7))];  // (m>>3) const per thread
                a_s[i][0] = v.x; a_s[i][1] = v.y; a_s[i][2] = v.z; a_s[i][3] = v.w;
            }
            float4 wl[4], wr[4];
            #pragma unroll
            for (int kj = 0; kj < 4; ++kj) {
                int k = kk * 4 + kj;
                int c = k & 7;
                int fl = tx ^ c;            // cols tx*4..+3
                wl[kj] = Ws[k * 32 + fl];
                wr[kj] = Ws[k * 32 + 16 + fl];  // cols 64+tx*4..+3
            }
            #pragma unroll
            for (int kj = 0; kj < 4; ++kj) {
                #pragma unroll
                for (int i = 0; i < 4; ++i) {
                    float av = a_s[i][kj];
                    fma4(accL[i], av, wl[kj]);
                    fma4(accR[i], av, wr[kj]);
                }
            }
        }
    }

    #pragma unroll
    for (int i = 0; i < 4; ++i) {
        int row = bm + ty * 4 + i;
        if (row < n) {
            *reinterpret_cast<float4*>(C + (size_t)row * 128 + tx * 4)      = accL[i];
            *reinterpret_cast<float4*>(C + (size_t)row * 128 + 64 + tx * 4) = accR[i];
        }
    }
}

// ---------------- aggregate ----------------
// out[i] = b + dinv[i]^2*h[i] + dinv[i] * sum_e (dinv[r]*w)*h[r]
// one 32-lane half-wave per node; lane holds float4 (16B) of the 512B row.
__global__ void k_aggregate(const float* __restrict__ h, const int* __restrict__ colptr,
                            const float2* __restrict__ epack,
                            const float* __restrict__ dinv, const float* __restrict__ bias,
                            float* __restrict__ out) {
    int node = (blockIdx.x * blockDim.x + threadIdx.x) >> 5;
    int lane = threadIdx.x & 31;
    if (node >= N_NODES) return;
    int s = colptr[node], e = colptr[node + 1];
    float di = dinv[node];
    float selfc = di * di;
    float4 hv = reinterpret_cast<const float4*>(h + (size_t)node * 128)[lane];
    float4 bb = reinterpret_cast<const float4*>(bias)[lane];
    float4 acc = make_float4(0.f, 0.f, 0.f, 0.f);   // edge sum (dinv[i] applied at end)
    // unroll x2: two independent gather chains in flight
    int j = s;
    for (; j + 1 < e; j += 2) {
        float2 p0 = epack[j];
        float2 p1 = epack[j + 1];
        int r0 = __float_as_int(p0.x);
        int r1 = __float_as_int(p1.x);
        float4 v0 = reinterpret_cast<const float4*>(h + (size_t)r0 * 128)[lane];
        float4 v1 = reinterpret_cast<const float4*>(h + (size_t)r1 * 128)[lane];
        fma4(acc, p0.y, v0);
        fma4(acc, p1.y, v1);
    }
    if (j < e) {
        float2 p0 = epack[j];
        int r0 = __float_as_int(p0.x);
        float4 v0 = reinterpret_cast<const float4*>(h + (size_t)r0 * 128)[lane];
        fma4(acc, p0.y, v0);
    }
    float4 o;
    o.x = bb.x + selfc * hv.x + di * acc.x;
    o.y = bb.y + selfc * hv.y + di * acc.y;
    o.z = bb.z + selfc * hv.z + di * acc.z;
    o.w = bb.w + selfc * hv.w + di * acc.w;
    reinterpret_cast<float4*>(out + (size_t)node * 128)[lane] = o;
}

// ---------------- mean pool, stage 1: segmented partial sums ----------------
__global__ void k_pool1(const float* __restrict__ h, const int* __restrict__ batch,
                        float* __restrict__ gsum) {
    int base = blockIdx.x * 128;
    int tid = threadIdx.x;
    int f = tid & 127, half = tid >> 7;
    int end = min(base + 128, N_NODES);
    float acc = 0.0f;
    int cur = -1;
    for (int i = base + half; i < end; i += 2) {
        int g = batch[i];
        if (g != cur) {
            if (cur >= 0) atomicAdd(&gsum[cur * 128 + f], acc);
            acc = 0.0f;
            cur = g;
        }
        acc += h[(size_t)i * 128 + f];
    }
    if (cur >= 0) atomicAdd(&gsum[cur * 128 + f], acc);
}

// ---------------- MLP head: mean-divide + 128 -> 64 -> 32 -> 2 ----------------
__device__ __forceinline__ int lbound(const int* b, int n, int v) {
    int lo = 0, hi = n;
    while (lo < hi) {
        int mid = (lo + hi) >> 1;
        if (b[mid] < v) lo = mid + 1; else hi = mid;
    }
    return lo;
}

__global__ void k_mlp(const float* __restrict__ gsum, const int* __restrict__ batch,
                      const float* __restrict__ fw1, const float* __restrict__ fb1,
                      const float* __restrict__ fw2, const float* __restrict__ fb2,
                      const float* __restrict__ fw3, const float* __restrict__ fb3,
                      float* __restrict__ out) {
    __shared__ float gs[128], h1[64], h2[32];
    __shared__ float rcnt;
    int graph = blockIdx.x;
    int tid = threadIdx.x;  // 64 threads
    if (tid == 0) {
        int lo = lbound(batch, N_NODES, graph);
        int hi = lbound(batch, N_NODES, graph + 1);
        rcnt = 1.0f / fmaxf((float)(hi - lo), 1.0f);
    }
    __syncthreads();
    float rc = rcnt;
    gs[tid]      = gsum[graph * 128 + tid] * rc;
    gs[tid + 64] = gsum[graph * 128 + 64 + tid] * rc;
    __syncthreads();
    float acc = fb1[tid];
    #pragma unroll 4
    for (int k = 0; k < 128; ++k) acc += gs[k] * fw1[k * 64 + tid];
    h1[tid] = leaky(acc);
    __syncthreads();
    if (tid < 32) {
        float a2 = fb2[tid];
        #pragma unroll 4
        for (int k = 0; k < 64; ++k) a2 += h1[k] * fw2[k * 32 + tid];
        h2[tid] = leaky(a2);
    }
    __syncthreads();
    if (tid < 2) {
        float a3 = fb3[tid];
        #pragma unroll
        for (int k = 0; k < 32; ++k) a3 += h2[k] * fw3[k * 2 + tid];
        out[graph * 2 + tid] = a3;
    }
}

// ---------------- launch ----------------
extern "C" void kernel_launch(void* const* d_in, const int* in_sizes, int n_in,
                              void* d_out, int out_size, void* d_ws, size_t ws_size,
                              hipStream_t stream) {
    const float* x   = (const float*)d_in[0];
    const int*   ei  = (const int*)d_in[1];    // int32 per harness contract
    const float* ew  = (const float*)d_in[2];
    const int*   bt  = (const int*)d_in[3];    // int32 per harness contract
    const float* W0 = (const float*)d_in[4];
    const float* b0 = (const float*)d_in[5];
    const float* W1 = (const float*)d_in[6];
    const float* b1 = (const float*)d_in[7];
    const float* W2 = (const float*)d_in[8];
    const float* b2 = (const float*)d_in[9];
    const float* fw1 = (const float*)d_in[10];
    const float* fb1 = (const float*)d_in[11];
    const float* fw2 = (const float*)d_in[12];
    const float* fb2 = (const float*)d_in[13];
    const float* fw3 = (const float*)d_in[14];
    const float* fb3 = (const float*)d_in[15];
    float* out = (float*)d_out;

    // workspace carve (512-B aligned)
    char* w = (char*)d_ws;
    size_t off = 0;
    auto carve = [&](size_t bytes) -> void* {
        void* p = w + off;
        off += (bytes + 511) & ~(size_t)511;
        return p;
    };
    unsigned long long* pack = (unsigned long long*)carve((size_t)N_NODES * 8);
    float*  dinv    = (float*)carve((size_t)N_NODES * 4);
    int*    cnt     = (int*)carve((size_t)N_NODES * 4);
    int*    colptr  = (int*)carve((size_t)(N_NODES + 1) * 4);
    int*    fillpos = (int*)carve((size_t)N_NODES * 4);
    int*    bsums   = (int*)carve(64 * 4);
    float2* epack   = (float2*)carve((size_t)N_EDGES * 8);
    float*  hA      = (float*)carve((size_t)N_NODES * FDIM * 4);
    float*  hB      = (float*)carve((size_t)N_NODES * FDIM * 4);
    float*  gsum    = (float*)carve((size_t)N_GRAPHS * FDIM * 4);
    (void)ws_size; (void)n_in; (void)in_sizes; (void)out_size;

    // ---- CSR build (once; shared by all 3 convs) ----
    hipMemsetAsync(pack, 0, (size_t)N_NODES * 8, stream);
    hipMemsetAsync(gsum, 0, (size_t)N_GRAPHS * FDIM * 4, stream);
    k_count<<<(N_EDGES + 255) / 256, 256, 0, stream>>>(ei, ew, pack);
    k_dinv<<<(N_NODES + 255) / 256, 256, 0, stream>>>(pack, dinv, cnt);
    k_scan1<<<40, 256, 0, stream>>>(cnt, bsums);
    k_scan2<<<1, 64, 0, stream>>>(bsums, colptr);
    k_scan3<<<40, 256, 0, stream>>>(cnt, bsums, colptr, fillpos);
    k_fill<<<(N_EDGES + 255) / 256, 256, 0, stream>>>(ei, ew, dinv, fillpos, epack);

    const int gemm_blocks = (N_NODES + 63) / 64;         // 625
    const int agg_blocks  = (N_NODES * 32 + 255) / 256;  // one 32-lane half-wave per node

    // conv1
    k_gemm<<<gemm_blocks, 256, 0, stream>>>(x, W0, hA, N_NODES, 0);
    k_aggregate<<<agg_blocks, 256, 0, stream>>>(hA, colptr, epack, dinv, b0, hB);
    // conv2 (leaky fused into GEMM input)
    k_gemm<<<gemm_blocks, 256, 0, stream>>>(hB, W1, hA, N_NODES, 1);
    k_aggregate<<<agg_blocks, 256, 0, stream>>>(hA, colptr, epack, dinv, b1, hB);
    // conv3
    k_gemm<<<gemm_blocks, 256, 0, stream>>>(hB, W2, hA, N_NODES, 1);
    k_aggregate<<<agg_blocks, 256, 0, stream>>>(hA, colptr, epack, dinv, b2, hB);

    // pool (parallel partial sums) + MLP (mean-divide fused)
    k_pool1<<<(N_NODES + 127) / 128, 256, 0, stream>>>(hB, bt, gsum);
    k_mlp<<<N_GRAPHS, 64, 0, stream>>>(gsum, bt, fw1, fb1, fw2, fb2, fw3, fb3, out);
}

// Round 15
// 444.128 us; speedup vs baseline: 1.3004x; 1.0034x over previous
//
#include <hip/hip_runtime.h>
#include <hip/hip_bf16.h>

#define N_NODES 40000
#define N_EDGES 640000
#define FDIM 128
#define N_GRAPHS 64
#define NEG_SLOPE 0.01f
#define DEG_SCALE 16777216.0f   // 2^24 fixed-point for packed degree
#define DEG_MASK  ((1ULL << 40) - 1)

// ---------------- helpers ----------------
__device__ __forceinline__ float leaky(float v) {
    return v > 0.0f ? v : NEG_SLOPE * v;
}
__device__ __forceinline__ void fma4(float4& d, float a, const float4& b) {
    d.x += a * b.x; d.y += a * b.y; d.z += a * b.z; d.w += a * b.w;
}
__device__ __forceinline__ int clamp_idx(int v) {
    return min(max(v, 0), N_NODES - 1);
}

// ---------------- CSR build ----------------
// NOTE: integer inputs are delivered as int32 by the harness (NOT int64).
// Single packed u64 atomic per edge: cnt in bits [40,64), deg (2^-24 fixed
// point) in bits [0,40). Max deg sum ~64*2^24 << 2^40 -> no overflow.
__global__ void k_count(const int* __restrict__ ei, const float* __restrict__ ew,
                        unsigned long long* __restrict__ pack) {
    int e = blockIdx.x * blockDim.x + threadIdx.x;
    if (e >= N_EDGES) return;
    int c = clamp_idx(ei[N_EDGES + e]);
    unsigned long long fp = (unsigned long long)__float2uint_rn(ew[e] * DEG_SCALE);
    atomicAdd(&pack[c], (1ULL << 40) | fp);
}

// decode pack -> dinv (float) and cnt (int) for the scan
__global__ void k_dinv(const unsigned long long* __restrict__ pack,
                       float* __restrict__ dinv, int* __restrict__ cnt) {
    int i = blockIdx.x * blockDim.x + threadIdx.x;
    if (i >= N_NODES) return;
    unsigned long long p = pack[i];
    float deg = (float)(p & DEG_MASK) * (1.0f / DEG_SCALE);
    dinv[i] = rsqrtf(deg + 1.0f);   // +1 self-loop weight
    cnt[i] = (int)(p >> 40);
}

// block sums of cnt over chunks of 1024
__global__ void k_scan1(const int* __restrict__ cnt, int* __restrict__ bsums) {
    __shared__ int sdata[256];
    int tid = threadIdx.x;
    int base = blockIdx.x * 1024 + tid * 4;
    int s = 0;
    #pragma unroll
    for (int j = 0; j < 4; ++j)
        if (base + j < N_NODES) s += cnt[base + j];
    sdata[tid] = s;
    __syncthreads();
    for (int off = 128; off > 0; off >>= 1) {
        if (tid < off) sdata[tid] += sdata[tid + off];
        __syncthreads();
    }
    if (tid == 0) bsums[blockIdx.x] = sdata[0];
}

// exclusive scan of 40 block sums (single thread; tiny)
__global__ void k_scan2(int* __restrict__ bsums, int* __restrict__ colptr) {
    if (threadIdx.x == 0 && blockIdx.x == 0) {
        int running = 0;
        for (int b = 0; b < 40; ++b) {
            int t = bsums[b];
            bsums[b] = running;
            running += t;
        }
        colptr[N_NODES] = running;   // == N_EDGES
    }
}

__global__ void k_scan3(const int* __restrict__ cnt, const int* __restrict__ bsums,
                        int* __restrict__ colptr, int* __restrict__ fillpos) {
    __shared__ int sdata[256];
    int tid = threadIdx.x;
    int base = blockIdx.x * 1024 + tid * 4;
    int v[4];
    int tsum = 0;
    #pragma unroll
    for (int j = 0; j < 4; ++j) {
        v[j] = (base + j < N_NODES) ? cnt[base + j] : 0;
        tsum += v[j];
    }
    sdata[tid] = tsum;
    __syncthreads();
    // Hillis-Steele inclusive scan over 256
    for (int off = 1; off < 256; off <<= 1) {
        int t = (tid >= off) ? sdata[tid - off] : 0;
        __syncthreads();
        sdata[tid] += t;
        __syncthreads();
    }
    int run = sdata[tid] - tsum + bsums[blockIdx.x];
    #pragma unroll
    for (int j = 0; j < 4; ++j) {
        if (base + j < N_NODES) {
            colptr[base + j] = run;
            fillpos[base + j] = run;
            run += v[j];
        }
    }
}

// packed edge record: .x = row index (int bits), .y = dinv[row]*w  (dinv[col]
// factored out of the per-edge coef; applied once per node in k_aggregate)
__global__ void k_fill(const int* __restrict__ ei, const float* __restrict__ ew,
                       const float* __restrict__ dinv, int* __restrict__ fillpos,
                       float2* __restrict__ epack) {
    int e = blockIdx.x * blockDim.x + threadIdx.x;
    if (e >= N_EDGES) return;
    int r = clamp_idx(ei[e]);
    int c = clamp_idx(ei[N_EDGES + e]);
    int pos = atomicAdd(&fillpos[c], 1);
    float2 p;
    p.x = __int_as_float(r);
    p.y = dinv[r] * ew[e];
    epack[pos] = p;
}

// ---------------- GEMM: C[n,128] = act(A[n,128]) @ W[128,128] ----------------
// BM=64 tile: LDS 48 KB -> 3 blocks/CU, grid 625.
__global__ __launch_bounds__(256) void k_gemm(const float* __restrict__ A,
                                              const float* __restrict__ W,
                                              float* __restrict__ C, int n, int act) {
    __shared__ float4 As[64 * 16];   // 16 KB: [m][k4] chunk of 64 k, swizzled
    __shared__ float4 Ws[64 * 32];   // 32 KB: [k][n4] chunk of 64 k, swizzled
    const int tid = threadIdx.x;
    const int bm = blockIdx.x * 64;
    const int tx = tid & 15, ty = tid >> 4;

    float4 accL[4], accR[4];
    #pragma unroll
    for (int i = 0; i < 4; ++i) {
        accL[i] = make_float4(0.f, 0.f, 0.f, 0.f);
        accR[i] = make_float4(0.f, 0.f, 0.f, 0.f);
    }

    for (int kt = 0; kt < 2; ++kt) {
        __syncthreads();
        // stage A chunk: 1024 float4s, 4 per thread (activation on load)
        for (int i = tid; i < 1024; i += 256) {
            int m = i >> 4, k4 = i & 15;
            int row = bm + m;
            float4 v = make_float4(0.f, 0.f, 0.f, 0.f);
            if (row < n) v = *reinterpret_cast<const float4*>(A + (size_t)row * 128 + kt * 64 + k4 * 4);
            if (act) { v.x = leaky(v.x); v.y = leaky(v.y); v.z = leaky(v.z); v.w = leaky(v.w); }
            As[m * 16 + (k4 ^ ((m >> 3) & 7))] = v;
        }
        // stage W chunk: 2048 float4s, 8 per thread
        for (int i = tid; i < 2048; i += 256) {
            int k = i >> 5, n4 = i & 31;
            float4 v = *reinterpret_cast<const float4*>(W + (size_t)(kt * 64 + k) * 128 + n4 * 4);
            Ws[k * 32 + (n4 ^ (k & 7))] = v;
        }
        __syncthreads();

        #pragma unroll
        for (int kk = 0; kk < 16; ++kk) {
            float a_s[4][4];
            #pragma unroll
            for (int i = 0; i < 4; ++i) {
                int m = ty * 4 + i;
                float4 v = As[m * 16 + (kk ^ ((m >> 3) & 7))];  // (m>>3) const per thread
                a_s[i][0] = v.x; a_s[i][1] = v.y; a_s[i][2] = v.z; a_s[i][3] = v.w;
            }
            float4 wl[4], wr[4];
            #pragma unroll
            for (int kj = 0; kj < 4; ++kj) {
                int k = kk * 4 + kj;
                int c = k & 7;
                int fl = tx ^ c;            // cols tx*4..+3
                wl[kj] = Ws[k * 32 + fl];
                wr[kj] = Ws[k * 32 + 16 + fl];  // cols 64+tx*4..+3
            }
            #pragma unroll
            for (int kj = 0; kj < 4; ++kj) {
                #pragma unroll
                for (int i = 0; i < 4; ++i) {
                    float av = a_s[i][kj];
                    fma4(accL[i], av, wl[kj]);
                    fma4(accR[i], av, wr[kj]);
                }
            }
        }
    }

    #pragma unroll
    for (int i = 0; i < 4; ++i) {
        int row = bm + ty * 4 + i;
        if (row < n) {
            *reinterpret_cast<float4*>(C + (size_t)row * 128 + tx * 4)      = accL[i];
            *reinterpret_cast<float4*>(C + (size_t)row * 128 + 64 + tx * 4) = accR[i];
        }
    }
}

// ---------------- aggregate ----------------
// out[i] = b + dinv[i]^2*h[i] + dinv[i] * sum_e (dinv[r]*w)*h[r]
// one 32-lane half-wave per node; lane holds float4 (16B) of the 512B row.
// unroll x4: FOUR independent gather chains in flight (was 2) — raises MLP;
// FMA accumulation order unchanged (numerics identical).
__global__ void k_aggregate(const float* __restrict__ h, const int* __restrict__ colptr,
                            const float2* __restrict__ epack,
                            const float* __restrict__ dinv, const float* __restrict__ bias,
                            float* __restrict__ out) {
    int node = (blockIdx.x * blockDim.x + threadIdx.x) >> 5;
    int lane = threadIdx.x & 31;
    if (node >= N_NODES) return;
    int s = colptr[node], e = colptr[node + 1];
    float di = dinv[node];
    float selfc = di * di;
    float4 hv = reinterpret_cast<const float4*>(h + (size_t)node * 128)[lane];
    float4 bb = reinterpret_cast<const float4*>(bias)[lane];
    float4 acc = make_float4(0.f, 0.f, 0.f, 0.f);   // edge sum (dinv[i] applied at end)
    int j = s;
    for (; j + 3 < e; j += 4) {
        float2 p0 = epack[j];
        float2 p1 = epack[j + 1];
        float2 p2 = epack[j + 2];
        float2 p3 = epack[j + 3];
        int r0 = __float_as_int(p0.x);
        int r1 = __float_as_int(p1.x);
        int r2 = __float_as_int(p2.x);
        int r3 = __float_as_int(p3.x);
        float4 v0 = reinterpret_cast<const float4*>(h + (size_t)r0 * 128)[lane];
        float4 v1 = reinterpret_cast<const float4*>(h + (size_t)r1 * 128)[lane];
        float4 v2 = reinterpret_cast<const float4*>(h + (size_t)r2 * 128)[lane];
        float4 v3 = reinterpret_cast<const float4*>(h + (size_t)r3 * 128)[lane];
        fma4(acc, p0.y, v0);
        fma4(acc, p1.y, v1);
        fma4(acc, p2.y, v2);
        fma4(acc, p3.y, v3);
    }
    for (; j < e; ++j) {
        float2 p0 = epack[j];
        int r0 = __float_as_int(p0.x);
        float4 v0 = reinterpret_cast<const float4*>(h + (size_t)r0 * 128)[lane];
        fma4(acc, p0.y, v0);
    }
    float4 o;
    o.x = bb.x + selfc * hv.x + di * acc.x;
    o.y = bb.y + selfc * hv.y + di * acc.y;
    o.z = bb.z + selfc * hv.z + di * acc.z;
    o.w = bb.w + selfc * hv.w + di * acc.w;
    reinterpret_cast<float4*>(out + (size_t)node * 128)[lane] = o;
}

// ---------------- mean pool, stage 1: segmented partial sums ----------------
__global__ void k_pool1(const float* __restrict__ h, const int* __restrict__ batch,
                        float* __restrict__ gsum) {
    int base = blockIdx.x * 128;
    int tid = threadIdx.x;
    int f = tid & 127, half = tid >> 7;
    int end = min(base + 128, N_NODES);
    float acc = 0.0f;
    int cur = -1;
    for (int i = base + half; i < end; i += 2) {
        int g = batch[i];
        if (g != cur) {
            if (cur >= 0) atomicAdd(&gsum[cur * 128 + f], acc);
            acc = 0.0f;
            cur = g;
        }
        acc += h[(size_t)i * 128 + f];
    }
    if (cur >= 0) atomicAdd(&gsum[cur * 128 + f], acc);
}

// ---------------- MLP head: mean-divide + 128 -> 64 -> 32 -> 2 ----------------
__device__ __forceinline__ int lbound(const int* b, int n, int v) {
    int lo = 0, hi = n;
    while (lo < hi) {
        int mid = (lo + hi) >> 1;
        if (b[mid] < v) lo = mid + 1; else hi = mid;
    }
    return lo;
}

__global__ void k_mlp(const float* __restrict__ gsum, const int* __restrict__ batch,
                      const float* __restrict__ fw1, const float* __restrict__ fb1,
                      const float* __restrict__ fw2, const float* __restrict__ fb2,
                      const float* __restrict__ fw3, const float* __restrict__ fb3,
                      float* __restrict__ out) {
    __shared__ float gs[128], h1[64], h2[32];
    __shared__ float rcnt;
    int graph = blockIdx.x;
    int tid = threadIdx.x;  // 64 threads
    if (tid == 0) {
        int lo = lbound(batch, N_NODES, graph);
        int hi = lbound(batch, N_NODES, graph + 1);
        rcnt = 1.0f / fmaxf((float)(hi - lo), 1.0f);
    }
    __syncthreads();
    float rc = rcnt;
    gs[tid]      = gsum[graph * 128 + tid] * rc;
    gs[tid + 64] = gsum[graph * 128 + 64 + tid] * rc;
    __syncthreads();
    float acc = fb1[tid];
    #pragma unroll 4
    for (int k = 0; k < 128; ++k) acc += gs[k] * fw1[k * 64 + tid];
    h1[tid] = leaky(acc);
    __syncthreads();
    if (tid < 32) {
        float a2 = fb2[tid];
        #pragma unroll 4
        for (int k = 0; k < 64; ++k) a2 += h1[k] * fw2[k * 32 + tid];
        h2[tid] = leaky(a2);
    }
    __syncthreads();
    if (tid < 2) {
        float a3 = fb3[tid];
        #pragma unroll
        for (int k = 0; k < 32; ++k) a3 += h2[k] * fw3[k * 2 + tid];
        out[graph * 2 + tid] = a3;
    }
}

// ---------------- launch ----------------
extern "C" void kernel_launch(void* const* d_in, const int* in_sizes, int n_in,
                              void* d_out, int out_size, void* d_ws, size_t ws_size,
                              hipStream_t stream) {
    const float* x   = (const float*)d_in[0];
    const int*   ei  = (const int*)d_in[1];    // int32 per harness contract
    const float* ew  = (const float*)d_in[2];
    const int*   bt  = (const int*)d_in[3];    // int32 per harness contract
    const float* W0 = (const float*)d_in[4];
    const float* b0 = (const float*)d_in[5];
    const float* W1 = (const float*)d_in[6];
    const float* b1 = (const float*)d_in[7];
    const float* W2 = (const float*)d_in[8];
    const float* b2 = (const float*)d_in[9];
    const float* fw1 = (const float*)d_in[10];
    const float* fb1 = (const float*)d_in[11];
    const float* fw2 = (const float*)d_in[12];
    const float* fb2 = (const float*)d_in[13];
    const float* fw3 = (const float*)d_in[14];
    const float* fb3 = (const float*)d_in[15];
    float* out = (float*)d_out;

    // workspace carve (512-B aligned)
    char* w = (char*)d_ws;
    size_t off = 0;
    auto carve = [&](size_t bytes) -> void* {
        void* p = w + off;
        off += (bytes + 511) & ~(size_t)511;
        return p;
    };
    unsigned long long* pack = (unsigned long long*)carve((size_t)N_NODES * 8);
    float*  dinv    = (float*)carve((size_t)N_NODES * 4);
    int*    cnt     = (int*)carve((size_t)N_NODES * 4);
    int*    colptr  = (int*)carve((size_t)(N_NODES + 1) * 4);
    int*    fillpos = (int*)carve((size_t)N_NODES * 4);
    int*    bsums   = (int*)carve(64 * 4);
    float2* epack   = (float2*)carve((size_t)N_EDGES * 8);
    float*  hA      = (float*)carve((size_t)N_NODES * FDIM * 4);
    float*  hB      = (float*)carve((size_t)N_NODES * FDIM * 4);
    float*  gsum    = (float*)carve((size_t)N_GRAPHS * FDIM * 4);
    (void)ws_size; (void)n_in; (void)in_sizes; (void)out_size;

    // ---- CSR build (once; shared by all 3 convs) ----
    hipMemsetAsync(pack, 0, (size_t)N_NODES * 8, stream);
    hipMemsetAsync(gsum, 0, (size_t)N_GRAPHS * FDIM * 4, stream);
    k_count<<<(N_EDGES + 255) / 256, 256, 0, stream>>>(ei, ew, pack);
    k_dinv<<<(N_NODES + 255) / 256, 256, 0, stream>>>(pack, dinv, cnt);
    k_scan1<<<40, 256, 0, stream>>>(cnt, bsums);
    k_scan2<<<1, 64, 0, stream>>>(bsums, colptr);
    k_scan3<<<40, 256, 0, stream>>>(cnt, bsums, colptr, fillpos);
    k_fill<<<(N_EDGES + 255) / 256, 256, 0, stream>>>(ei, ew, dinv, fillpos, epack);

    const int gemm_blocks = (N_NODES + 63) / 64;         // 625
    const int agg_blocks  = (N_NODES * 32 + 255) / 256;  // one 32-lane half-wave per node

    // conv1
    k_gemm<<<gemm_blocks, 256, 0, stream>>>(x, W0, hA, N_NODES, 0);
    k_aggregate<<<agg_blocks, 256, 0, stream>>>(hA, colptr, epack, dinv, b0, hB);
    // conv2 (leaky fused into GEMM input)
    k_gemm<<<gemm_blocks, 256, 0, stream>>>(hB, W1, hA, N_NODES, 1);
    k_aggregate<<<agg_blocks, 256, 0, stream>>>(hA, colptr, epack, dinv, b1, hB);
    // conv3
    k_gemm<<<gemm_blocks, 256, 0, stream>>>(hB, W2, hA, N_NODES, 1);
    k_aggregate<<<agg_blocks, 256, 0, stream>>>(hA, colptr, epack, dinv, b2, hB);

    // pool (parallel partial sums) + MLP (mean-divide fused)
    k_pool1<<<(N_NODES + 127) / 128, 256, 0, stream>>>(hB, bt, gsum);
    k_mlp<<<N_GRAPHS, 64, 0, stream>>>(gsum, bt, fw1, fb1, fw2, fb2, fw3, fb3, out);
}